// Round 2
// baseline (60.138 us; speedup 1.0000x reference)
//
#include <hip/hip_runtime.h>
#include <hip/hip_bf16.h>

// Tensor-train gather: out[q] = sum_{a,b} g0[0,i0,a] * g1[a,i1,b] * g2[b,i2,0]
// g0: (1,320,16) -> [i0*16 + a]
// g1: (16,320,16) -> [a*5120 + i1*16 + b]
// g2: (16,320,1) -> [b*320 + i2]
//
// Lane mapping (16 lanes per query, 4 queries per wave64): lane a owns ROW a
// of the 16x16 G1 slice -> 64 B contiguous, loaded as 4x float4 (per 16-lane
// group that's 1 KB fully-coalesced). g2 column is fetched one element per
// lane and redistributed with width-16 shuffles (VALU, no memory traffic).
// out[q] = reduce_a( g0[a] * sum_b( g1[a,b] * g2[b] ) ).

__global__ __launch_bounds__(256) void tt_gather_kernel(
    const float* __restrict__ g0,
    const float* __restrict__ g1,
    const float* __restrict__ g2,
    const int* __restrict__ idxs,
    float* __restrict__ out,
    int N)
{
    int tid = blockIdx.x * blockDim.x + threadIdx.x;
    int q = tid >> 4;        // query index
    int a = tid & 15;        // lane's row of the G1 slice
    if (q >= N) return;

    const int i0 = idxs[3 * q + 0];
    const int i1 = idxs[3 * q + 1];
    const int i2 = idxs[3 * q + 2];

    const float g0v = g0[i0 * 16 + a];          // broadcast-friendly (4 addrs/wave)
    const float g2v = g2[a * 320 + i2];         // lane a holds g2 column elem a

    const float4* __restrict__ g1r =
        (const float4*)(g1 + a * 5120 + i1 * 16);   // 16B-aligned, 64B/lane
    const float4 r0 = g1r[0];
    const float4 r1 = g1r[1];
    const float4 r2 = g1r[2];
    const float4 r3 = g1r[3];

    const float row[16] = {r0.x, r0.y, r0.z, r0.w,
                           r1.x, r1.y, r1.z, r1.w,
                           r2.x, r2.y, r2.z, r2.w,
                           r3.x, r3.y, r3.z, r3.w};

    // s = sum_b g1[a,b] * g2[b]; g2[b] pulled from lane b via width-16 shuffle
    float s = 0.0f;
#pragma unroll
    for (int b = 0; b < 16; ++b) {
        s = fmaf(row[b], __shfl(g2v, b, 16), s);
    }

    float p = g0v * s;

    // Reduce across the 16-lane group
#pragma unroll
    for (int off = 8; off >= 1; off >>= 1) {
        p += __shfl_xor(p, off, 16);
    }

    if (a == 0) out[q] = p;
}

extern "C" void kernel_launch(void* const* d_in, const int* in_sizes, int n_in,
                              void* d_out, int out_size, void* d_ws, size_t ws_size,
                              hipStream_t stream) {
    const float* g0 = (const float*)d_in[0];
    const float* g1 = (const float*)d_in[1];
    const float* g2 = (const float*)d_in[2];
    const int* idxs = (const int*)d_in[3];
    float* out = (float*)d_out;

    const int N = in_sizes[3] / 3;       // 8192 queries
    const int threads = N * 16;          // 16 lanes per query
    const int block = 256;
    const int grid = (threads + block - 1) / block;

    tt_gather_kernel<<<grid, block, 0, stream>>>(g0, g1, g2, idxs, out, N);
}